// Round 6
// baseline (1171.885 us; speedup 1.0000x reference)
//
#include <hip/hip_runtime.h>
#include <hip/hip_bf16.h>
#include <stdint.h>

#define BB 2
#define SS 1024
#define VV 513
#define VP 576          // 513 padded to 9*64
#define DD 512
#define HH 8
#define DKK 64
#define DFFN 2048
#define LL 6
#define MM (BB * SS)    // 2048

typedef __bf16 bf16x8 __attribute__((ext_vector_type(8)));
typedef float f32x4 __attribute__((ext_vector_type(4)));
typedef unsigned short us8 __attribute__((ext_vector_type(8)));

static __device__ inline unsigned short f2bf(float f) {
  union { float f; unsigned u; } v; v.f = f;
  unsigned u = v.u;
  unsigned r = (u + 0x7FFFu + ((u >> 16) & 1u)) >> 16;
  return (unsigned short)r;
}

static __device__ inline bf16x8 ldfrag(const unsigned short* p) {
  us8 r = *(const us8*)p;
  return __builtin_bit_cast(bf16x8, r);
}

typedef __attribute__((address_space(3))) void lds_void;
typedef const __attribute__((address_space(1))) void glb_void;
static __device__ inline void gl_lds16(const void* g, void* l) {
  __builtin_amdgcn_global_load_lds((glb_void*)g, (lds_void*)l, 16, 0, 0);
}

// swizzled LDS fragment read: tile rows are linear 128B, byte ^= (row&7)<<4
// (matches pre-swizzled global source in staging)
static __device__ inline bf16x8 ldfrag_swz(const unsigned short* base, int row, int kloc) {
  const unsigned byte = (unsigned)(row * 128 + kloc * 2) ^ (unsigned)((row & 7) << 4);
  return ldfrag((const unsigned short*)((const char*)base + byte));
}

static __device__ inline int rot3(int x) { return (x == 2) ? 0 : x + 1; }

// ---------------------------------------------------------------------------
// GEMM: C = A[M][Kp](bf16) * B^T, B stored [N][Kp] bf16 (padded).
// 3-deep counted-vmcnt pipeline, raw barriers. NT = tile N (64 or 128).
// ---------------------------------------------------------------------------
struct GemmP {
  const unsigned short* A;
  const unsigned short* B0; const unsigned short* B1; const unsigned short* B2;
  const float* bias;
  float* C;
  unsigned short* D0; unsigned short* D1; unsigned short* D2;
  int Kp, Np, ldc, Nreal, relu;
};

template<int NB, int NT>
__global__ __launch_bounds__(256)
void gemm_tpl(GemmP p)
{
  constexpr int FN = NT / 32;        // b-fragments per wave
  __shared__ unsigned short Al[3][64 * 64];
  __shared__ unsigned short Bl[3][NT * 64];
  const int tid = threadIdx.x;
  const int l = tid & 63, w = tid >> 6;
  const int wm = w >> 1, wn = w & 1;
  const int lr = l & 15, lg = l >> 4;

  const int nbn = p.Np / NT;
  int sel = 0, bx = blockIdx.x;
  if (NB > 1) { sel = bx / nbn; bx -= sel * nbn; }
  const unsigned short* Bmat = p.B0;
  if (NB > 1 && sel == 1) Bmat = p.B1;
  if (NB > 2 && sel == 2) Bmat = p.B2;
  const int m0 = blockIdx.y << 6, n0 = bx * NT;

  f32x4 acc[2][FN];
  const f32x4 zf = {0.f, 0.f, 0.f, 0.f};
#pragma unroll
  for (int i = 0; i < 2; ++i)
#pragma unroll
    for (int j = 0; j < FN; ++j) acc[i][j] = zf;

  const size_t Kp = (size_t)p.Kp;
  const unsigned short* Abase = p.A + (size_t)m0 * Kp;
  const unsigned short* Bbase = Bmat + (size_t)n0 * Kp;

  auto stage = [&](int buf, int kt) {
    const int k0 = kt << 6;
#pragma unroll
    for (int j = 0; j < 2; ++j) {
      const int ti = j * 256 + tid;
      const int row = ti >> 3;
      const int ch = (ti & 7) ^ (row & 7);
      gl_lds16(Abase + (size_t)row * Kp + k0 + ch * 8, &Al[buf][ti * 8]);
    }
#pragma unroll
    for (int j = 0; j < FN; ++j) {
      const int ti = j * 256 + tid;
      const int row = ti >> 3;
      const int ch = (ti & 7) ^ (row & 7);
      gl_lds16(Bbase + (size_t)row * Kp + k0 + ch * 8, &Bl[buf][ti * 8]);
    }
  };

  const int nt = p.Kp >> 6;
  stage(0, 0);
  if (nt > 1) stage(1, 1);
  int cb = 0, sb = 2;

  for (int kt = 0; kt < nt; ++kt) {
    if (kt + 1 < nt) {
      if constexpr (FN == 2) asm volatile("s_waitcnt vmcnt(4)" ::: "memory");
      else                   asm volatile("s_waitcnt vmcnt(6)" ::: "memory");
    } else {
      asm volatile("s_waitcnt vmcnt(0)" ::: "memory");
    }
    __builtin_amdgcn_s_barrier();
    if (kt + 2 < nt) { stage(sb, kt + 2); sb = rot3(sb); }
#pragma unroll
    for (int ks = 0; ks < 2; ++ks) {
      bf16x8 af[2], bfv[FN];
#pragma unroll
      for (int mf = 0; mf < 2; ++mf)
        af[mf] = ldfrag_swz(Al[cb], wm * 32 + mf * 16 + lr, ks * 32 + lg * 8);
#pragma unroll
      for (int nf = 0; nf < FN; ++nf)
        bfv[nf] = ldfrag_swz(Bl[cb], wn * (NT / 2) + nf * 16 + lr, ks * 32 + lg * 8);
#pragma unroll
      for (int mf = 0; mf < 2; ++mf)
#pragma unroll
        for (int nf = 0; nf < FN; ++nf)
          acc[mf][nf] = __builtin_amdgcn_mfma_f32_16x16x32_bf16(af[mf], bfv[nf], acc[mf][nf], 0, 0, 0);
    }
    cb = rot3(cb);
  }

  unsigned short* Dsel = p.D0;
  if (NB > 1 && sel == 1) Dsel = p.D1;
  if (NB > 2 && sel == 2) Dsel = p.D2;
#pragma unroll
  for (int mf = 0; mf < 2; ++mf) {
#pragma unroll
    for (int r = 0; r < 4; ++r) {
      const int grow = m0 + wm * 32 + mf * 16 + (lg << 2) + r;
#pragma unroll
      for (int nf = 0; nf < FN; ++nf) {
        const int gcol = n0 + wn * (NT / 2) + nf * 16 + lr;
        float v = acc[mf][nf][r];
        if (p.bias && gcol < p.Nreal) v += p.bias[gcol];
        if (p.relu) v = fmaxf(v, 0.f);
        if (Dsel) Dsel[(size_t)grow * p.Np + gcol] = f2bf(v);
        if (p.C && gcol < p.Nreal) p.C[(size_t)grow * p.ldc + gcol] = v;
      }
    }
  }
}

// ---------------------------------------------------------------------------
// Batched GEMM over 12 (B,D) pairs sharing A. Np=Kp=512, bf16 out only.
// ---------------------------------------------------------------------------
struct GemmBat {
  const unsigned short* A;
  const unsigned short* B[12];
  unsigned short* D[12];
  int Kp, Np;
};

__global__ __launch_bounds__(256)
void gemm_bat(GemmBat p)
{
  __shared__ unsigned short Al[3][64 * 64];
  __shared__ unsigned short Bl[3][64 * 64];
  const int tid = threadIdx.x;
  const int l = tid & 63, w = tid >> 6;
  const int wm = w >> 1, wn = w & 1;
  const int lr = l & 15, lg = l >> 4;

  const int nbn = p.Np >> 6;
  const int sel = blockIdx.x / nbn;
  const int bx = blockIdx.x - sel * nbn;
  const unsigned short* Bmat = p.B[sel];
  unsigned short* Dmat = p.D[sel];
  const int m0 = blockIdx.y << 6, n0 = bx << 6;

  f32x4 acc[2][2];
  const f32x4 zf = {0.f, 0.f, 0.f, 0.f};
#pragma unroll
  for (int i = 0; i < 2; ++i)
#pragma unroll
    for (int j = 0; j < 2; ++j) acc[i][j] = zf;

  const size_t Kp = (size_t)p.Kp;
  const unsigned short* Abase = p.A + (size_t)m0 * Kp;
  const unsigned short* Bbase = Bmat + (size_t)n0 * Kp;

  auto stage = [&](int buf, int kt) {
    const int k0 = kt << 6;
#pragma unroll
    for (int j = 0; j < 2; ++j) {
      const int ti = j * 256 + tid;
      const int row = ti >> 3;
      const int ch = (ti & 7) ^ (row & 7);
      gl_lds16(Abase + (size_t)row * Kp + k0 + ch * 8, &Al[buf][ti * 8]);
    }
#pragma unroll
    for (int j = 0; j < 2; ++j) {
      const int ti = j * 256 + tid;
      const int row = ti >> 3;
      const int ch = (ti & 7) ^ (row & 7);
      gl_lds16(Bbase + (size_t)row * Kp + k0 + ch * 8, &Bl[buf][ti * 8]);
    }
  };

  const int nt = p.Kp >> 6;
  stage(0, 0);
  if (nt > 1) stage(1, 1);
  int cb = 0, sb = 2;

  for (int kt = 0; kt < nt; ++kt) {
    if (kt + 1 < nt) asm volatile("s_waitcnt vmcnt(4)" ::: "memory");
    else             asm volatile("s_waitcnt vmcnt(0)" ::: "memory");
    __builtin_amdgcn_s_barrier();
    if (kt + 2 < nt) { stage(sb, kt + 2); sb = rot3(sb); }
#pragma unroll
    for (int ks = 0; ks < 2; ++ks) {
      bf16x8 af[2], bfv[2];
#pragma unroll
      for (int mf = 0; mf < 2; ++mf)
        af[mf] = ldfrag_swz(Al[cb], wm * 32 + mf * 16 + lr, ks * 32 + lg * 8);
#pragma unroll
      for (int nf = 0; nf < 2; ++nf)
        bfv[nf] = ldfrag_swz(Bl[cb], wn * 32 + nf * 16 + lr, ks * 32 + lg * 8);
#pragma unroll
      for (int mf = 0; mf < 2; ++mf)
#pragma unroll
        for (int nf = 0; nf < 2; ++nf)
          acc[mf][nf] = __builtin_amdgcn_mfma_f32_16x16x32_bf16(af[mf], bfv[nf], acc[mf][nf], 0, 0, 0);
    }
    cb = rot3(cb);
  }

#pragma unroll
  for (int mf = 0; mf < 2; ++mf) {
#pragma unroll
    for (int r = 0; r < 4; ++r) {
      const int grow = m0 + wm * 32 + mf * 16 + (lg << 2) + r;
#pragma unroll
      for (int nf = 0; nf < 2; ++nf) {
        const int gcol = n0 + wn * 32 + nf * 16 + lr;
        Dmat[(size_t)grow * p.Np + gcol] = f2bf(acc[mf][nf][r]);
      }
    }
  }
}

// ---------------------------------------------------------------------------
// V transpose: src + li*MM*DD, [B*S][512] -> dst + li*MM*DD as [B][H][64][1024]
// ---------------------------------------------------------------------------
__global__ __launch_bounds__(256)
void vtrans_kernel(const unsigned short* __restrict__ src, unsigned short* __restrict__ dst)
{
  __shared__ unsigned short t[64][72];
  const int s0 = blockIdx.x << 6, h = blockIdx.y;
  const int b = blockIdx.z & 1, li = blockIdx.z >> 1;
  const unsigned short* vb = src + (size_t)li * MM * DD;
  unsigned short* vbT = dst + (size_t)li * MM * DD;
  const int tid = threadIdx.x;
  const int rr = tid >> 2, cbase = (tid & 3) * 2;
#pragma unroll
  for (int j = 0; j < 2; ++j) {
    const int ch = cbase + j;
    *(us8*)&t[rr][ch * 8] = *(const us8*)(vb + ((size_t)(b * SS) + s0 + rr) * DD + h * DKK + ch * 8);
  }
  __syncthreads();
#pragma unroll
  for (int j = 0; j < 2; ++j) {
    const int ch = cbase + j;
    us8 o;
#pragma unroll
    for (int e = 0; e < 8; ++e) o[e] = t[ch * 8 + e][rr];
    *(us8*)(vbT + (((size_t)(b * HH) + h) * DKK + rr) * SS + s0 + ch * 8) = o;
  }
}

// ---------------------------------------------------------------------------
// Flash attention: QBLK=32, 2 waves, 3-deep counted-vmcnt staging pipeline.
// V pre-transposed. O written in-place over Q.
// ---------------------------------------------------------------------------
template<int CAUSAL>
__global__ __launch_bounds__(128)
void attn_kernel(const unsigned short* __restrict__ Qb,
                 const unsigned short* __restrict__ Kb,
                 const unsigned short* __restrict__ VbT,
                 unsigned short* __restrict__ Ob,
                 const float* __restrict__ maskadd)
{
  __shared__ unsigned short Kl[3][64 * 64];
  __shared__ unsigned short Vl[3][64 * 64];
  __shared__ unsigned short Pl[2 * 16 * 72];
  const int tid = threadIdx.x;
  const int l = tid & 63, w = tid >> 6;
  const int qt = blockIdx.x, h = blockIdx.y, b = blockIdx.z;
  const int lr = l & 15, lg = l >> 4;
  const int qbase = qt * 32 + w * 16;

  bf16x8 qf[2];
  {
    const unsigned short* qrow = Qb + ((size_t)(b * SS) + qbase + lr) * DD + h * DKK;
    qf[0] = ldfrag(qrow + (lg << 3));
    qf[1] = ldfrag(qrow + 32 + (lg << 3));
  }

  const unsigned short* Kbase = Kb + (size_t)(b * SS) * DD + h * DKK;
  const unsigned short* Vbase = VbT + ((size_t)(b * HH) + h) * DKK * SS;

  auto stage = [&](int buf, int kt) {
#pragma unroll
    for (int j = 0; j < 4; ++j) {
      const int ti = j * 128 + tid;
      const int row = ti >> 3;
      const int ch = (ti & 7) ^ (row & 7);
      gl_lds16(Kbase + (size_t)(kt * 64 + row) * DD + ch * 8, &Kl[buf][ti * 8]);
    }
#pragma unroll
    for (int j = 0; j < 4; ++j) {
      const int ti = j * 128 + tid;
      const int row = ti >> 3;
      const int ch = (ti & 7) ^ (row & 7);
      gl_lds16(Vbase + (size_t)row * SS + kt * 64 + ch * 8, &Vl[buf][ti * 8]);
    }
  };

  f32x4 accO[4];
  const f32x4 zf = {0.f, 0.f, 0.f, 0.f};
#pragma unroll
  for (int i = 0; i < 4; ++i) accO[i] = zf;
  float mold[4] = {-1e30f, -1e30f, -1e30f, -1e30f};
  float lsum[4] = {0.f, 0.f, 0.f, 0.f};

  const int ktmax = CAUSAL ? ((qt >> 1) + 1) : (SS / 64);
  stage(0, 0);
  if (ktmax > 1) stage(1, 1);
  int cb = 0, sb = 2;

  for (int kt = 0; kt < ktmax; ++kt) {
    if (kt + 1 < ktmax) asm volatile("s_waitcnt vmcnt(8)" ::: "memory");
    else                asm volatile("s_waitcnt vmcnt(0)" ::: "memory");
    __builtin_amdgcn_s_barrier();
    if (kt + 2 < ktmax) { stage(sb, kt + 2); sb = rot3(sb); }
    // QK^T
    float sc[4][4];
    __builtin_amdgcn_s_setprio(1);
#pragma unroll
    for (int nf = 0; nf < 4; ++nf) {
      f32x4 s = zf;
      bf16x8 k0 = ldfrag_swz(Kl[cb], nf * 16 + lr, lg * 8);
      bf16x8 k1 = ldfrag_swz(Kl[cb], nf * 16 + lr, 32 + lg * 8);
      s = __builtin_amdgcn_mfma_f32_16x16x32_bf16(qf[0], k0, s, 0, 0, 0);
      s = __builtin_amdgcn_mfma_f32_16x16x32_bf16(qf[1], k1, s, 0, 0, 0);
      const int kglob = kt * 64 + nf * 16 + lr;
      const float madd = maskadd[b * SS + kglob];
#pragma unroll
      for (int r = 0; r < 4; ++r) {
        const int qglob = qbase + (lg << 2) + r;
        sc[nf][r] = (CAUSAL && kglob > qglob) ? -1e9f : s[r] * 0.125f + madd;
      }
    }
    __builtin_amdgcn_s_setprio(0);
    // online softmax (rows live in 16-lane groups)
#pragma unroll
    for (int r = 0; r < 4; ++r) {
      float mloc = fmaxf(fmaxf(sc[0][r], sc[1][r]), fmaxf(sc[2][r], sc[3][r]));
#pragma unroll
      for (int off = 1; off < 16; off <<= 1)
        mloc = fmaxf(mloc, __shfl_xor(mloc, off, 64));
      const float mnew = fmaxf(mold[r], mloc);
      const float corr = __expf(mold[r] - mnew);
      float ps = 0.f;
#pragma unroll
      for (int nf = 0; nf < 4; ++nf) {
        const float pv = __expf(sc[nf][r] - mnew);
        sc[nf][r] = pv;
        ps += pv;
      }
#pragma unroll
      for (int off = 1; off < 16; off <<= 1)
        ps += __shfl_xor(ps, off, 64);
      lsum[r] = lsum[r] * corr + ps;
#pragma unroll
      for (int nf = 0; nf < 4; ++nf) accO[nf][r] *= corr;
      mold[r] = mnew;
    }
    // P transpose via per-wave LDS region (in-wave ordering only)
    unsigned short* pw = &Pl[w * 16 * 72];
#pragma unroll
    for (int nf = 0; nf < 4; ++nf)
#pragma unroll
      for (int r = 0; r < 4; ++r)
        pw[((lg << 2) + r) * 72 + nf * 16 + lr] = f2bf(sc[nf][r]);
    bf16x8 pa0 = ldfrag(&pw[lr * 72 + (lg << 3)]);
    bf16x8 pa1 = ldfrag(&pw[lr * 72 + 32 + (lg << 3)]);
    // PV
    __builtin_amdgcn_s_setprio(1);
#pragma unroll
    for (int nf = 0; nf < 4; ++nf) {
      bf16x8 v0 = ldfrag_swz(Vl[cb], nf * 16 + lr, lg * 8);
      bf16x8 v1 = ldfrag_swz(Vl[cb], nf * 16 + lr, 32 + lg * 8);
      accO[nf] = __builtin_amdgcn_mfma_f32_16x16x32_bf16(pa0, v0, accO[nf], 0, 0, 0);
      accO[nf] = __builtin_amdgcn_mfma_f32_16x16x32_bf16(pa1, v1, accO[nf], 0, 0, 0);
    }
    __builtin_amdgcn_s_setprio(0);
    cb = rot3(cb);
  }
#pragma unroll
  for (int r = 0; r < 4; ++r) {
    const float inv = 1.f / lsum[r];
    const size_t orow = ((size_t)(b * SS) + qbase + (lg << 2) + r) * DD + h * DKK;
#pragma unroll
    for (int nf = 0; nf < 4; ++nf)
      Ob[orow + nf * 16 + lr] = f2bf(accO[nf][r] * inv);
  }
}

// ---------------------------------------------------------------------------
// out = LN(a + c); 4 rows per block, vectorized
// ---------------------------------------------------------------------------
__global__ __launch_bounds__(256)
void addln_kernel(const float* __restrict__ a, const float* __restrict__ c,
                  const float* __restrict__ g, const float* __restrict__ bb,
                  float* __restrict__ hf, unsigned short* __restrict__ hb)
{
  const int row = blockIdx.x * 4 + (threadIdx.x >> 6);
  const int l = threadIdx.x & 63;
  const float* ar = a + (size_t)row * DD + l * 8;
  const float* cr = c + (size_t)row * DD + l * 8;
  f32x4 x0 = *(const f32x4*)ar + *(const f32x4*)cr;
  f32x4 x1 = *(const f32x4*)(ar + 4) + *(const f32x4*)(cr + 4);
  float sum = x0[0] + x0[1] + x0[2] + x0[3] + x1[0] + x1[1] + x1[2] + x1[3];
#pragma unroll
  for (int off = 1; off < 64; off <<= 1) sum += __shfl_xor(sum, off, 64);
  const float mean = sum * (1.f / 512.f);
  float vs = 0.f;
#pragma unroll
  for (int j = 0; j < 4; ++j) { float d0 = x0[j] - mean; float d1 = x1[j] - mean; vs += d0 * d0 + d1 * d1; }
#pragma unroll
  for (int off = 1; off < 64; off <<= 1) vs += __shfl_xor(vs, off, 64);
  const float rs = rsqrtf(vs * (1.f / 512.f) + 1e-6f);
  const f32x4 g0 = *(const f32x4*)(g + l * 8), g1 = *(const f32x4*)(g + l * 8 + 4);
  const f32x4 b0 = *(const f32x4*)(bb + l * 8), b1 = *(const f32x4*)(bb + l * 8 + 4);
  f32x4 o0, o1;
  us8 ob;
#pragma unroll
  for (int j = 0; j < 4; ++j) {
    o0[j] = (x0[j] - mean) * rs * g0[j] + b0[j];
    o1[j] = (x1[j] - mean) * rs * g1[j] + b1[j];
    ob[j] = f2bf(o0[j]); ob[j + 4] = f2bf(o1[j]);
  }
  float* of = hf + (size_t)row * DD + l * 8;
  *(f32x4*)of = o0; *(f32x4*)(of + 4) = o1;
  *(us8*)(hb + (size_t)row * DD + l * 8) = ob;
}

// row-valid -> additive mask (0 or -1e9)
__global__ __launch_bounds__(64)
void rowvalid_kernel(const float* __restrict__ x, int n, float* __restrict__ out)
{
  const int row = blockIdx.x, l = threadIdx.x;
  const float* xr = x + (size_t)row * n;
  int ok = 1;
  for (int j = l; j < n; j += 64) ok &= (xr[j] != -1.0f) ? 1 : 0;
  ok = __all(ok) ? 1 : 0;
  if (l == 0) out[row] = ok ? 0.f : -1e9f;
}

// transposed sinusoid table: tabT[d][s] bf16
__global__ void postable_kernel(unsigned short* __restrict__ tabT)
{
  const int i = blockIdx.x * blockDim.x + threadIdx.x;
  if (i >= DD * SS) return;
  const int d = i >> 10, s = i & 1023;
  const float ex = (float)(2 * (d >> 1)) * (1.0f / (float)DD);
  const float ang = (float)s * exp2f(ex * -13.287712379549449f);
  tabT[i] = f2bf((d & 1) ? cosf(ang) : sinf(ang));
}

__global__ void gpec_kernel(const float* __restrict__ gk, unsigned short* __restrict__ Mb)
{
  const int i = blockIdx.x * blockDim.x + threadIdx.x;
  if (i >= BB * SS * SS) return;
  const int b = i / (SS * SS);
  const int rem = i - b * (SS * SS);
  const float* p = gk + (size_t)b * 3 * SS * SS + rem;
  Mb[i] = f2bf((p[0] + 0.9f * p[SS * SS] + 0.81f * p[2 * SS * SS]) * (1.0f / 2.71f));
}

// W [L][K][N] f32 -> WT [L][Np][Kp] bf16, zero-padded (generic, guarded)
__global__ __launch_bounds__(256)
void wconv_kernel(const float* __restrict__ W, unsigned short* __restrict__ WT,
                  int K, int N, int Kp, int Np)
{
  __shared__ float t[64][65];
  const float* Wl = W + (size_t)blockIdx.z * K * N;
  unsigned short* WTl = WT + (size_t)blockIdx.z * Np * Kp;
  const int n0 = blockIdx.x << 6, k0 = blockIdx.y << 6;
  const int tid = threadIdx.x;
  const int cx = tid & 63, ry = tid >> 6;
#pragma unroll
  for (int i = 0; i < 16; ++i) {
    const int kk = k0 + ry + i * 4, nn = n0 + cx;
    t[ry + i * 4][cx] = (kk < K && nn < N) ? Wl[(size_t)kk * N + nn] : 0.f;
  }
  __syncthreads();
#pragma unroll
  for (int i = 0; i < 16; ++i) {
    const int nn = n0 + ry + i * 4, kk = k0 + cx;
    WTl[(size_t)nn * Kp + kk] = f2bf(t[cx][ry + i * 4]);
  }
}

// 8 attention weight sets [L][512][512] in one launch; z = wi*LL + li
struct WconvB { const float* W[8]; unsigned short* WT[8]; };
__global__ __launch_bounds__(256)
void wconv8_kernel(WconvB p)
{
  __shared__ float t[64][65];
  const int z = blockIdx.z;
  const int wi = z / LL, li = z - wi * LL;
  const float* Wl = p.W[wi] + (size_t)li * DD * DD;
  unsigned short* WTl = p.WT[wi] + (size_t)li * DD * DD;
  const int n0 = blockIdx.x << 6, k0 = blockIdx.y << 6;
  const int cx = threadIdx.x & 63, ry = threadIdx.x >> 6;
#pragma unroll
  for (int i = 0; i < 16; ++i)
    t[ry + i * 4][cx] = Wl[(size_t)(k0 + ry + i * 4) * DD + n0 + cx];
  __syncthreads();
#pragma unroll
  for (int i = 0; i < 16; ++i)
    WTl[(size_t)(n0 + ry + i * 4) * DD + k0 + cx] = f2bf(t[cx][ry + i * 4]);
}

__global__ void aconv_kernel(const float* __restrict__ A, unsigned short* __restrict__ Ab,
                             int N, int Np, int total)
{
  const int i = blockIdx.x * blockDim.x + threadIdx.x;
  if (i >= total) return;
  const int row = i / Np, col = i - row * Np;
  Ab[i] = (col < N) ? f2bf(A[(size_t)row * N + col]) : (unsigned short)0;
}

// ---------------------------------------------------------------------------
static inline void g1(hipStream_t s, const unsigned short* A, const unsigned short* B,
                      const float* bias, float* C, unsigned short* D,
                      int Kp, int Np, int ldc, int Nreal, int relu)
{
  GemmP p{};
  p.A = A; p.B0 = B; p.bias = bias; p.C = C; p.D0 = D;
  p.Kp = Kp; p.Np = Np; p.ldc = ldc; p.Nreal = Nreal; p.relu = relu;
  gemm_tpl<1, 64><<<dim3(Np >> 6, MM >> 6), 256, 0, s>>>(p);
}

// wide-tile variant for N divisible by 128
static inline void g1w(hipStream_t s, const unsigned short* A, const unsigned short* B,
                       const float* bias, unsigned short* D, int Kp, int Np, int relu)
{
  GemmP p{};
  p.A = A; p.B0 = B; p.bias = bias; p.D0 = D;
  p.Kp = Kp; p.Np = Np; p.ldc = Np; p.Nreal = Np; p.relu = relu;
  gemm_tpl<1, 128><<<dim3(Np >> 7, MM >> 6), 256, 0, s>>>(p);
}

static inline void g3(hipStream_t s, const unsigned short* A, const unsigned short* B0,
                      const unsigned short* B1, const unsigned short* B2,
                      unsigned short* D0, unsigned short* D1, unsigned short* D2,
                      int Kp, int Np)
{
  GemmP p{};
  p.A = A; p.B0 = B0; p.B1 = B1; p.B2 = B2; p.D0 = D0; p.D1 = D1; p.D2 = D2;
  p.Kp = Kp; p.Np = Np; p.ldc = Np; p.Nreal = Np; p.relu = 0;
  gemm_tpl<3, 64><<<dim3(3 * (Np >> 6), MM >> 6), 256, 0, s>>>(p);
}

extern "C" void kernel_launch(void* const* d_in, const int* in_sizes, int n_in,
                              void* d_out, int out_size, void* d_ws, size_t ws_size,
                              hipStream_t stream)
{
  (void)in_sizes; (void)n_in; (void)out_size; (void)ws_size;
  const float* dec_in = (const float*)d_in[0];
  const float* prev   = (const float*)d_in[1];
  const float* gk     = (const float*)d_in[6];
  const float* emb_w1 = (const float*)d_in[7];
  const float* emb_b1 = (const float*)d_in[8];
  const float* emb_w2 = (const float*)d_in[9];
  const float* emb_b2 = (const float*)d_in[10];
  const float* emb_w3 = (const float*)d_in[11];
  const float* emb_b3 = (const float*)d_in[12];
  const float* ln0_g  = (const float*)d_in[13];
  const float* ln0_b  = (const float*)d_in[14];
  const float* wq     = (const float*)d_in[15];
  const float* wk     = (const float*)d_in[16];
  const float* wv     = (const float*)d_in[17];
  const float* wo     = (const float*)d_in[18];
  const float* cq     = (const float*)d_in[19];
  const float* ck     = (const float*)d_in[20];
  const float* cv     = (const float*)d_in[21];
  const float* co     = (const float*)d_in[22];
  const float* ffn_w1 = (const float*)d_in[23];
  const float* ffn_w2 = (const float*)d_in[24];
  const float* ffn_b1 = (const float*)d_in[25];
  const float* ffn_b2 = (const float*)d_in[26];
  const float* ln1_g  = (const float*)d_in[27];
  const float* ln1_b  = (const float*)d_in[28];
  const float* ln2_g  = (const float*)d_in[29];
  const float* ln2_b  = (const float*)d_in[30];
  const float* ln3_g  = (const float*)d_in[31];
  const float* ln3_b  = (const float*)d_in[32];
  const float* p_w1   = (const float*)d_in[33];
  const float* p_b1   = (const float*)d_in[34];
  const float* p_w2   = (const float*)d_in[35];
  const float* p_b2   = (const float*)d_in[36];
  const float* p_w3   = (const float*)d_in[37];
  const float* p_b3   = (const float*)d_in[38];

  // ---- workspace carve ----
  char* wsp = (char*)d_ws;
  auto carve = [&](size_t bytes) { char* r = wsp; wsp += (bytes + 255) & ~(size_t)255; return r; };

  unsigned short* decb  = (unsigned short*)carve((size_t)MM * VP * 2);
  unsigned short* prevb = (unsigned short*)carve((size_t)MM * DD * 2);
  float*          hf    = (float*)carve((size_t)MM * DD * 4);
  unsigned short* hb    = (unsigned short*)carve((size_t)MM * DD * 2);
  float*          xf1   = (float*)carve((size_t)MM * DD * 4);
  unsigned short* tb1   = (unsigned short*)carve((size_t)MM * DFFN * 2);   // 8 MB
  unsigned short* Mbb   = tb1;                                   // alias: first 4 MB
  float*          xf2   = (float*)((char*)tb1 + (size_t)MM * SS * 2);      // alias: last 4 MB
  unsigned short* tb2a  = (unsigned short*)carve((size_t)MM * VP * 2);
  unsigned short* tb2b  = (unsigned short*)carve((size_t)MM * VP * 2);
  unsigned short* qb    = (unsigned short*)carve((size_t)MM * DD * 2);
  unsigned short* kb    = (unsigned short*)carve((size_t)MM * DD * 2);
  unsigned short* vb    = (unsigned short*)carve((size_t)MM * DD * 2);
  unsigned short* vbT   = (unsigned short*)carve((size_t)MM * DD * 2);
  float* kvs = (float*)carve((size_t)MM * 4);
  float* kve = (float*)carve((size_t)MM * 4);
  unsigned short* postabt = (unsigned short*)carve((size_t)DD * SS * 2);
  unsigned short* ew1t  = (unsigned short*)carve((size_t)VP * VP * 2);
  unsigned short* ew2t  = (unsigned short*)carve((size_t)VP * VP * 2);
  unsigned short* ew3t  = (unsigned short*)carve((size_t)DD * VP * 2);
  unsigned short* wqt   = (unsigned short*)carve((size_t)LL * DD * DD * 2);
  unsigned short* wkt   = (unsigned short*)carve((size_t)LL * DD * DD * 2);
  unsigned short* wvt   = (unsigned short*)carve((size_t)LL * DD * DD * 2);
  unsigned short* wot   = (unsigned short*)carve((size_t)LL * DD * DD * 2);
  unsigned short* cqt   = (unsigned short*)carve((size_t)LL * DD * DD * 2);
  unsigned short* ckt   = (unsigned short*)carve((size_t)LL * DD * DD * 2);
  unsigned short* cvt   = (unsigned short*)carve((size_t)LL * DD * DD * 2);
  unsigned short* cot   = (unsigned short*)carve((size_t)LL * DD * DD * 2);
  unsigned short* f1t   = (unsigned short*)carve((size_t)LL * DFFN * DD * 2);
  unsigned short* f2t   = (unsigned short*)carve((size_t)LL * DD * DFFN * 2);
  unsigned short* p1t   = (unsigned short*)carve((size_t)VP * DD * 2);
  unsigned short* p2t   = (unsigned short*)carve((size_t)VP * VP * 2);
  unsigned short* p3t   = (unsigned short*)carve((size_t)VP * VP * 2);
  unsigned short* ckall = (unsigned short*)carve((size_t)LL * MM * DD * 2);  // 12 MB
  unsigned short* cvall = (unsigned short*)carve((size_t)LL * MM * DD * 2);  // 12 MB
  unsigned short* cvbT  = (unsigned short*)carve((size_t)LL * MM * DD * 2);  // 12 MB

  const dim3 agrid(SS / 32, HH, BB);

  // ---- prep ----
  rowvalid_kernel<<<MM, 64, 0, stream>>>(dec_in, VV, kvs);
  rowvalid_kernel<<<MM, 64, 0, stream>>>(prev, DD, kve);
  aconv_kernel<<<(MM * VP + 255) / 256, 256, 0, stream>>>(dec_in, decb, VV, VP, MM * VP);
  aconv_kernel<<<(MM * DD + 255) / 256, 256, 0, stream>>>(prev, prevb, DD, DD, MM * DD);
  postable_kernel<<<(DD * SS + 255) / 256, 256, 0, stream>>>(postabt);
  gpec_kernel<<<(BB * SS * SS + 255) / 256, 256, 0, stream>>>(gk, Mbb);

  {
    WconvB wb{};
    wb.W[0] = wq; wb.W[1] = wk; wb.W[2] = wv; wb.W[3] = wo;
    wb.W[4] = cq; wb.W[5] = ck; wb.W[6] = cv; wb.W[7] = co;
    wb.WT[0] = wqt; wb.WT[1] = wkt; wb.WT[2] = wvt; wb.WT[3] = wot;
    wb.WT[4] = cqt; wb.WT[5] = ckt; wb.WT[6] = cvt; wb.WT[7] = cot;
    wconv8_kernel<<<dim3(8, 8, 8 * LL), 256, 0, stream>>>(wb);
  }
  wconv_kernel<<<dim3(9, 9, 1), 256, 0, stream>>>(emb_w1, ew1t, VV, VV, VP, VP);
  wconv_kernel<<<dim3(9, 9, 1), 256, 0, stream>>>(emb_w2, ew2t, VV, VV, VP, VP);
  wconv_kernel<<<dim3(8, 9, 1), 256, 0, stream>>>(emb_w3, ew3t, VV, DD, VP, DD);
  wconv_kernel<<<dim3(32, 8, LL), 256, 0, stream>>>(ffn_w1, f1t, DD, DFFN, DD, DFFN);
  wconv_kernel<<<dim3(8, 32, LL), 256, 0, stream>>>(ffn_w2, f2t, DFFN, DD, DFFN, DD);
  wconv_kernel<<<dim3(9, 8, 1), 256, 0, stream>>>(p_w1, p1t, DD, VV, DD, VP);
  wconv_kernel<<<dim3(9, 9, 1), 256, 0, stream>>>(p_w2, p2t, VV, VV, VP, VP);
  wconv_kernel<<<dim3(9, 9, 1), 256, 0, stream>>>(p_w3, p3t, VV, VV, VP, VP);

  // ---- all 6 layers' cross-attention K/V in one batched GEMM + transpose ----
  {
    GemmBat p{};
    p.A = prevb; p.Kp = DD; p.Np = DD;
    for (int i = 0; i < LL; ++i) {
      p.B[2 * i]     = ckt + (size_t)i * DD * DD;
      p.B[2 * i + 1] = cvt + (size_t)i * DD * DD;
      p.D[2 * i]     = ckall + (size_t)i * MM * DD;
      p.D[2 * i + 1] = cvall + (size_t)i * MM * DD;
    }
    gemm_bat<<<dim3(12 * (DD >> 6), MM >> 6), 256, 0, stream>>>(p);
    vtrans_kernel<<<dim3(16, 8, 2 * LL), 256, 0, stream>>>(cvall, cvbT);
  }

  // ---- embedding MLP + graph positional encoding ----
  g1(stream, decb, ew1t, emb_b1, nullptr, tb2a, VP, VP, VP, VV, 1);
  g1(stream, tb2a, ew2t, emb_b2, nullptr, tb2b, VP, VP, VP, VV, 1);
  g1(stream, tb2b, ew3t, emb_b3, xf1, nullptr, VP, DD, DD, DD, 0);
  g1(stream, Mbb, postabt, nullptr, xf2, nullptr, SS, DD, DD, DD, 0);
  addln_kernel<<<MM / 4, 256, 0, stream>>>(xf1, xf2, ln0_g, ln0_b, hf, hb);

  for (int i = 0; i < LL; ++i) {
    const size_t od = (size_t)i * DD * DD;
    // self attention
    g3(stream, hb, wqt + od, wkt + od, wvt + od, qb, kb, vb, DD, DD);
    vtrans_kernel<<<dim3(16, 8, 2), 256, 0, stream>>>(vb, vbT);
    attn_kernel<1><<<agrid, 128, 0, stream>>>(qb, kb, vbT, qb, kvs);
    g1(stream, qb, wot + od, nullptr, xf1, nullptr, DD, DD, DD, DD, 0);
    addln_kernel<<<MM / 4, 256, 0, stream>>>(hf, xf1, ln1_g + i * DD, ln1_b + i * DD, hf, hb);
    // cross attention (K/V precomputed)
    g1(stream, hb, cqt + od, nullptr, nullptr, qb, DD, DD, DD, DD, 0);
    attn_kernel<0><<<agrid, 128, 0, stream>>>(qb, ckall + (size_t)i * MM * DD,
                                              cvbT + (size_t)i * MM * DD, qb, kve);
    g1(stream, qb, cot + od, nullptr, xf1, nullptr, DD, DD, DD, DD, 0);
    addln_kernel<<<MM / 4, 256, 0, stream>>>(hf, xf1, ln2_g + i * DD, ln2_b + i * DD, hf, hb);
    // FFN
    g1w(stream, hb, f1t + (size_t)i * DFFN * DD, ffn_b1 + i * DFFN, tb1, DD, DFFN, 1);
    g1(stream, tb1, f2t + (size_t)i * DD * DFFN, ffn_b2 + i * DD, xf1, nullptr, DFFN, DD, DD, DD, 0);
    addln_kernel<<<MM / 4, 256, 0, stream>>>(hf, xf1, ln3_g + i * DD, ln3_b + i * DD, hf, hb);
  }

  // ---- output head ----
  g1(stream, hb, p1t, p_b1, nullptr, tb2a, DD, VP, VP, VV, 1);
  g1(stream, tb2a, p2t, p_b2, nullptr, tb2b, VP, VP, VP, VV, 1);
  g1(stream, tb2b, p3t, p_b3, (float*)d_out, nullptr, VP, VP, VV, VV, 0);
}